// Round 6
// baseline (247.704 us; speedup 1.0000x reference)
//
#include <hip/hip_runtime.h>

// Banded stereo cost volume via MFMA band-GEMM, all 3 scales in ONE launch.
// cost[j,h,x] = G_h[x][y=x-j],  G_h = L_h^T * R_h  (K = C = 32).
// Per block: one h, one 64-wide x-chunk, full D. 4 waves; wave w owns x-tile w.
// One mfma_f32_16x16x32_bf16 per 16x16 G-tile (K=32 in one instruction).
// Stores remain full 256B row-segments (round 5 fixed L2-set write thrash).

typedef float  vf4  __attribute__((ext_vector_type(4)));
typedef short  s8v  __attribute__((ext_vector_type(8)));   // 8 bf16 bit patterns
typedef float  f4a  __attribute__((ext_vector_type(4)));   // MFMA C/D

__device__ __forceinline__ unsigned short f2bf(float f) {   // RTNE fp32->bf16
    unsigned u = __builtin_bit_cast(unsigned, f);
    return (unsigned short)((u + 0x7FFFu + ((u >> 16) & 1u)) >> 16);
}

// smem layout: phase1 Lt[64][40] bf16 (5120B) + Rt[NR][40] bf16 (<=20480B)
//              phase2 Gs[80][64] f32 (20480B) aliased on top. 25600B total.
#define SMEM_BYTES 25600

template<int W, int H, int D, int NT, int NR>   // NT = D/16, NR = D+64
__device__ __forceinline__ void run_scale(const float* __restrict__ L,
                                          const float* __restrict__ R,
                                          float* __restrict__ out,
                                          int h, int x0,
                                          unsigned short* Lt, unsigned short* Rt,
                                          float* Gs)
{
    const int t    = threadIdx.x;
    const int lane = t & 63;
    const int w    = t >> 6;      // wave = x-tile index (0..3)
    const int n    = lane & 15;
    const int quad = lane >> 4;
    const size_t HW = (size_t)H * W;
    const int yb = x0 - D;        // y window base (tile-aligned, may be <0)

    // ---- stage Lt[x][c] (bf16, row stride 40 for conflict-free b128 reads) ----
    {
        const float* Lb = L + (size_t)h * W + x0;
        #pragma unroll
        for (int it = 0; it < 2; ++it) {
            int c  = (t >> 4) + it * 16;
            int x4 = (t & 15) * 4;
            vf4 v = *(const vf4*)(Lb + (size_t)c * HW + x4);
            #pragma unroll
            for (int i = 0; i < 4; ++i)
                Lt[(x4 + i) * 40 + c] = f2bf(v[i]);
        }
    }
    // ---- stage Rt[y][c]; rows with y<0 are never read (whole tiles skipped) ----
    {
        const float* Rb = R + (size_t)h * W + yb;
        constexpr int NV  = NR / 4;        // vf4 per channel
        constexpr int TOT = 32 * NV;
        #pragma unroll
        for (int it = 0; it < (TOT + 255) / 256; ++it) {
            int v = t + it * 256;
            if (v < TOT) {
                int c = v / NV, q = v - c * NV;
                int y4 = 4 * q;
                if (yb + y4 >= 0) {
                    vf4 x = *(const vf4*)(Rb + (size_t)c * HW + y4);
                    #pragma unroll
                    for (int i = 0; i < 4; ++i)
                        Rt[(y4 + i) * 40 + c] = f2bf(x[i]);
                }
            }
        }
    }
    __syncthreads();

    // ---- MFMA: NT+1 y-tiles per x-tile; acc in regs ----
    f4a acc[NT + 1];
    #pragma unroll
    for (int s = 0; s <= NT; ++s) acc[s] = (f4a)(0.f);

    // A[m=lane&15][k=quad*8+j] ; B[k=quad*8+j][n=lane&15]  (m89-verified layouts)
    const s8v a = *(const s8v*)&Lt[(w * 16 + n) * 40 + quad * 8];
    #pragma unroll
    for (int s = 0; s <= NT; ++s) {
        const int rt = w + s;                       // global y-tile index from yb
        if (yb + rt * 16 >= 0) {                    // tile-aligned zero region: skip
            s8v b = *(const s8v*)&Rt[(rt * 16 + n) * 40 + quad * 8];
            acc[s] = __builtin_amdgcn_mfma_f32_16x16x32_bf16(a, b, acc[s], 0, 0, 0);
        }
    }
    __syncthreads();    // Lt/Rt dead; Gs aliases the same smem

    // ---- shear flush: per 16-j tile, G tiles -> Gs (swizzled) -> row stores ----
    #pragma unroll
    for (int jt = 0; jt < NT; ++jt) {
        #pragma unroll
        for (int d = 0; d < 2; ++d) {
            const int s  = NT - 1 - jt + d;         // compile-time (loops unrolled)
            const int yi = (w + d) * 16 + n;        // 0..79
            const int ch = (w * 4 + quad) ^ (yi & 15);  // XOR bank swizzle
            *(vf4*)&Gs[yi * 64 + ch * 4] = acc[s];
        }
        __syncthreads();
        float vals[4];
        #pragma unroll
        for (int rr = 0; rr < 4; ++rr) {
            const int jj = w * 4 + rr;
            const int yi = lane - jj + 16;          // 1..79
            vals[rr] = Gs[yi * 64 + (((lane >> 2) ^ (yi & 15)) << 2) + (lane & 3)];
        }
        #pragma unroll
        for (int rr = 0; rr < 4; ++rr) {
            const int j = jt * 16 + w * 4 + rr;
            __builtin_nontemporal_store(vals[rr],
                out + ((size_t)j * H + h) * W + x0 + lane);  // 256B/wave, full lines
        }
        __syncthreads();
    }
}

// Grid: scale0 [0,2048): 8 xc x 256 h ; scale1 [2048,2560): 4 x 128 ;
//       scale2 [2560,2688): 2 x 64.
__global__ __launch_bounds__(256, 6)
void cost_volume_mfma(const float* __restrict__ L0, const float* __restrict__ R0,
                      const float* __restrict__ L1, const float* __restrict__ R1,
                      const float* __restrict__ L2, const float* __restrict__ R2,
                      float* __restrict__ out)
{
    __shared__ __align__(16) char smem[SMEM_BYTES];
    unsigned short* Lt = (unsigned short*)smem;
    unsigned short* Rt = Lt + 64 * 40;
    float* Gs = (float*)smem;

    const int id = blockIdx.x;
    if (id < 2048) {
        run_scale<512, 256, 192, 12, 256>(L0, R0, out,
                                          id >> 3, (id & 7) * 64, Lt, Rt, Gs);
    } else if (id < 2560) {
        const int r = id - 2048;
        run_scale<256, 128, 96, 6, 160>(L1, R1, out + 25165824,
                                        r >> 2, (r & 3) * 64, Lt, Rt, Gs);
    } else {
        const int r = id - 2560;
        run_scale<128, 64, 48, 3, 112>(L2, R2, out + 28311552,
                                       r >> 1, (r & 1) * 64, Lt, Rt, Gs);
    }
}

extern "C" void kernel_launch(void* const* d_in, const int* in_sizes, int n_in,
                              void* d_out, int out_size, void* d_ws, size_t ws_size,
                              hipStream_t stream)
{
    const float* L0 = (const float*)d_in[0];
    const float* R0 = (const float*)d_in[1];
    const float* L1 = (const float*)d_in[2];
    const float* R1 = (const float*)d_in[3];
    const float* L2 = (const float*)d_in[4];
    const float* R2 = (const float*)d_in[5];
    float* out = (float*)d_out;

    cost_volume_mfma<<<dim3(2688), dim3(256), 0, stream>>>(
        L0, R0, L1, R1, L2, R2, out);
}

// Round 7
// 189.194 us; speedup vs baseline: 1.3093x; 1.3093x over previous
//
#include <hip/hip_runtime.h>

// Banded stereo cost volume via MFMA band-GEMM, one launch, wave-autonomous.
// cost[j,h,x] = G_h[x][y=x-j], G_h = L_h^T R_h (K=C=32), mfma_f32_16x16x32_bf16.
// Block: one h, 64-x chunk, full D. Wave w owns j-tiles {w, w+4, w+8,...}:
// computes its own diagonal G tiles (2 live accs -> no spill; R6 spilled
// acc[13] to scratch = +126MB HBM), shears through a WAVE-PRIVATE Gs region
// (no barriers after staging), stores 256B/instr full lines (R5-verified).
// Staging: c-pair packed b32 writes, x=xp+16k lanes -> 2-way banks (free);
// R6's scalar u16 staging was 16-way conflicted (9M cycles).

typedef float vf4 __attribute__((ext_vector_type(4)));
typedef short s8v __attribute__((ext_vector_type(8)));

__device__ __forceinline__ unsigned short f2bf(float f) {   // RTNE fp32->bf16
    unsigned u = __builtin_bit_cast(unsigned, f);
    return (unsigned short)((u + 0x7FFFu + ((u >> 16) & 1u)) >> 16);
}

// LDS map (bytes): Lt u16[64][40] = 5120 | Rt u16[256][40] = 20480 |
//                  Gs f32: 4 waves x 2480 = 39680.  Total 65280 <= 64KB.
#define RT_OFF 2560          // u16 index of Rt
#define GS_F_OFF 6400        // float index of Gs
#define GS_WSTR 2480         // floats per wave
#define GS_XSTR 620          // floats per xt (31 rows x 20)
#define GS_ROWP 20           // floats per yl row

template<int W, int H, int D, int NT, int NR>   // NT=D/16, NR=D+64
__device__ __forceinline__ void run_scale(const float* __restrict__ L,
                                          const float* __restrict__ R,
                                          float* __restrict__ out,
                                          int h, int x0,
                                          unsigned short* sm16, float* smf)
{
    const int t  = threadIdx.x;
    const int xp = t & 15;
    const int cp = t >> 4;                 // c-pair 0..15
    const size_t HW = (size_t)H * W;
    const int yb = x0 - D;                 // y window base (mult of 16)

    // ---- stage Lt[x][c] bf16, stride 40 u16; b32 c-pair writes, 2-way banks ----
    {
        const float* Lc0 = L + (size_t)(2 * cp) * HW + (size_t)h * W + x0;
        const float* Lc1 = Lc0 + HW;
        #pragma unroll
        for (int k = 0; k < 4; ++k) {
            int x = xp + 16 * k;
            unsigned v = (unsigned)f2bf(Lc0[x]) | ((unsigned)f2bf(Lc1[x]) << 16);
            *(unsigned*)&sm16[x * 40 + 2 * cp] = v;
        }
    }
    // ---- stage Rt[y][c]; y<0 columns zero-filled (exact zero region) ----
    {
        const float* Rc0 = R + (size_t)(2 * cp) * HW + (size_t)h * W + yb;
        const float* Rc1 = Rc0 + HW;
        #pragma unroll
        for (int k = 0; k < NR / 16; ++k) {
            int y = xp + 16 * k;
            unsigned v = 0u;
            if (yb + y >= 0)
                v = (unsigned)f2bf(Rc0[y]) | ((unsigned)f2bf(Rc1[y]) << 16);
            *(unsigned*)&sm16[RT_OFF + y * 40 + 2 * cp] = v;
        }
    }
    __syncthreads();   // the only barrier

    const int lane = t & 63;
    const int w    = t >> 6;
    const int n    = lane & 15;
    const int q    = lane >> 4;

    // A-frags for all 4 x-tiles (R6-verified layout): A[m=n][k=q*8+j]
    s8v a[4];
    #pragma unroll
    for (int xt = 0; xt < 4; ++xt)
        a[xt] = *(const s8v*)&sm16[(16 * xt + n) * 40 + 8 * q];

    float* gw = smf + GS_F_OFF + w * GS_WSTR;      // wave-private Gs
    const int xt_r = lane >> 4, xl = lane & 15;
    const float* gr = gw + xt_r * GS_XSTR + xl;

    for (int jt = w; jt < NT; jt += 4) {
        // -- compute diagonal band: per xt, tiles rt0/rt0+1; write to Gs --
        #pragma unroll
        for (int xt = 0; xt < 4; ++xt) {
            const int rt0 = NT + xt - jt - 1;
            vf4 acc0 = (vf4)(0.f), acc1 = (vf4)(0.f);
            if (yb + 16 * rt0 >= 0) {
                s8v b = *(const s8v*)&sm16[RT_OFF + (16 * rt0 + n) * 40 + 8 * q];
                acc0 = __builtin_amdgcn_mfma_f32_16x16x32_bf16(a[xt], b, acc0, 0, 0, 0);
            }
            if (yb + 16 * (rt0 + 1) >= 0) {
                s8v b = *(const s8v*)&sm16[RT_OFF + (16 * rt0 + 16 + n) * 40 + 8 * q];
                acc1 = __builtin_amdgcn_mfma_f32_16x16x32_bf16(a[xt], b, acc1, 0, 0, 0);
            }
            // C/D: lane holds y-local=n, x-locals 4q..4q+3 (contiguous -> b128).
            // Pair-row Y = n+16d stored at row Y-1 (rows 1..31 used -> 0..30).
            float* gx = gw + xt * GS_XSTR;
            if (n > 0)
                *(vf4*)&gx[(n - 1) * GS_ROWP + 4 * q] = acc0;
            *(vf4*)&gx[(n + 15) * GS_ROWP + 4 * q] = acc1;
        }
        // -- shear read (yl = xl-jl+15 in [0,30]) + full-row 256B NT stores --
        #pragma unroll
        for (int jl = 0; jl < 16; ++jl) {
            float v = gr[(xl - jl + 15) * GS_ROWP];
            __builtin_nontemporal_store(
                v, out + ((size_t)(16 * jt + jl) * H + h) * W + x0 + lane);
        }
    }
}

// Grid: scale0 [0,2048): 8 xc x 256 h ; scale1 [2048,2560): 4 x 128 ;
//       scale2 [2560,2688): 2 x 64.
__global__ __launch_bounds__(256, 2)
void cost_volume_mfma(const float* __restrict__ L0, const float* __restrict__ R0,
                      const float* __restrict__ L1, const float* __restrict__ R1,
                      const float* __restrict__ L2, const float* __restrict__ R2,
                      float* __restrict__ out)
{
    __shared__ __align__(16) char smem[65280];
    unsigned short* sm16 = (unsigned short*)smem;
    float* smf = (float*)smem;

    const int id = blockIdx.x;
    if (id < 2048) {
        run_scale<512, 256, 192, 12, 256>(L0, R0, out,
                                          id >> 3, (id & 7) * 64, sm16, smf);
    } else if (id < 2560) {
        const int r = id - 2048;
        run_scale<256, 128, 96, 6, 160>(L1, R1, out + 25165824,
                                        r >> 2, (r & 3) * 64, sm16, smf);
    } else {
        const int r = id - 2560;
        run_scale<128, 64, 48, 3, 112>(L2, R2, out + 28311552,
                                       r >> 1, (r & 1) * 64, sm16, smf);
    }
}

extern "C" void kernel_launch(void* const* d_in, const int* in_sizes, int n_in,
                              void* d_out, int out_size, void* d_ws, size_t ws_size,
                              hipStream_t stream)
{
    const float* L0 = (const float*)d_in[0];
    const float* R0 = (const float*)d_in[1];
    const float* L1 = (const float*)d_in[2];
    const float* R1 = (const float*)d_in[3];
    const float* L2 = (const float*)d_in[4];
    const float* R2 = (const float*)d_in[5];
    float* out = (float*)d_out;

    cost_volume_mfma<<<dim3(2688), dim3(256), 0, stream>>>(
        L0, R0, L1, R1, L2, R2, out);
}